// Round 10
// baseline (8662.555 us; speedup 1.0000x reference)
//
#include <hip/hip_runtime.h>

// LSTMClassification: B=64, T=512, IN=128, H=512, 2 layers + FC(512->1)
// Round 10 = round-9 champion body (4-wave, fragment-loaded-once, proven MFMA
// addressing) with ONE change: sync mechanism = canary data-polling.
//   Producers: cell phase stores h as 256 x 4B bypass atomics, fire-and-forget
//     (NO vmcnt drain, NO flag store, NO post-publish barrier).
//   Consumers: issue coalesced loads; SWEEP-validate: if any of a lane's words
//     == canary (0xFF80 = -inf bf16, unreachable for |h|<1), reload the lane's
//     whole group coalesced (one RT per sweep; no per-word predication -- that
//     was round-7's serialization disaster).
//   Chain per step: store-visible (~0.5 RT) + consumer sweep (1 RT), down from
//     round-9's drain + flag-visible + poll + load (~3.5 RT = the 6.1us step).
// Buffers: hrec0[t][wg][64][8] step-indexed (L0 out; L0 recurrence reads t-1,
//   L1 input reads t) -- canary-filled by prep each launch (graph-replay safe).
//   L1 recurrence: ring[8] slots; WG w re-canaries its own 1KB of slot (t-4)&7
//   during step t (readers of t-4 are >= step t-1; re-canary retires through
//   3 steps of sweep-vmcnt(0)s before slot reuse at t+4 -> never-stale).
// Validation order: recurrence first, MFMA it (useful work) while the other
// layer's input lands, then validate input. 2 barriers/step (gbuf WAR + ready).
// All cross-WG ops = __hip_atomic_* AGENT scope (only proven-coherent grade).

#define NWG 64
#define NB 64
#define NT 512
#define NH 512
#define BLK 512                 // elements per WG h-block (64 batches x 8 cols)
#define SREC (NWG * BLK)        // elements per step slot = 32768 (64KB)
#define RING 8
#define CAN32 0xFF80FF80u

typedef float f32x4 __attribute__((ext_vector_type(4)));
typedef __bf16 bf16x4 __attribute__((ext_vector_type(4)));
typedef __bf16 bf16x8 __attribute__((ext_vector_type(8)));
typedef unsigned long long u64;
typedef unsigned u32;

__device__ __forceinline__ u64 lda8(const __bf16* p) {
    return __hip_atomic_load((const u64*)p, __ATOMIC_RELAXED, __HIP_MEMORY_SCOPE_AGENT);
}
__device__ __forceinline__ void sta4(u32* p, u32 v) {
    __hip_atomic_store(p, v, __ATOMIC_RELAXED, __HIP_MEMORY_SCOPE_AGENT);
}
__device__ __forceinline__ unsigned short bfbits(float f) {
    __bf16 h = (__bf16)f; unsigned short u; __builtin_memcpy(&u, &h, 2); return u;
}

__global__ void prep_kernel(u64* hrec0, u64* ring, u64* hinit) {
    const u64 C = 0xFF80FF80FF80FF80ull;
    const size_t stride = (size_t)gridDim.x * blockDim.x;
    const size_t i = (size_t)blockIdx.x * blockDim.x + threadIdx.x;
    const size_t n0 = (size_t)NT * SREC / 4;        // 4,194,304 u64 (33.5MB)
    for (size_t k = i; k < n0; k += stride) hrec0[k] = C;
    if (i < (size_t)RING * SREC / 4) ring[i] = C;   // 64K u64 (512KB)
    if (i < SREC / 4) hinit[i] = 0;                 // zero h_{-1}
}

// issue 2N coalesced 8B loads for one operand group (block layout)
template<int N>
__device__ __forceinline__ void issue_group(const __bf16* hp, int aoff, int bsub, u64* w) {
    #pragma unroll
    for (int kk = 0; kk < N; ++kk) {
        const __bf16* b = hp + (4 * kk + bsub) * BLK + aoff;
        w[2 * kk]     = lda8(b);
        w[2 * kk + 1] = lda8(b + 2 * BLK);
    }
}

// sweep-validate: while any of this lane's words is canary, reload the WHOLE
// group coalesced (one RT per sweep; per-lane exit, no cross-lane ops).
template<int N>
__device__ __forceinline__ void sweep_validate(const __bf16* hp, int aoff, int bsub, u64* w) {
    int g = 0;
    for (;;) {
        u32 bad = 0;
        #pragma unroll
        for (int k = 0; k < 2 * N; ++k)
            bad |= ((u32)w[k] == CAN32) | ((u32)(w[k] >> 32) == CAN32);
        if (!bad) break;
        if (++g > (1 << 20)) break;   // safety: never hard-hang
        issue_group<N>(hp, aoff, bsub, w);
    }
}

template<int KIH, int IS_L0>
__device__ __forceinline__ void layer_body(
    char* Wl, float (*gbuf)[36], int wg,
    const float* __restrict__ W_ih, const float* __restrict__ W_hh,
    const float* __restrict__ b_ih, const float* __restrict__ b_hh,
    const float* __restrict__ x_f32,       // L0: x [NB][NT][KIH] fp32 (cached)
    __bf16* __restrict__ hrec0,            // [NT][NWG][BLK] step-indexed
    __bf16* __restrict__ ring,             // [RING][NWG][BLK] L1 recurrence
    const __bf16* __restrict__ hinit,      // zero block [NWG][BLK]
    float* __restrict__ h_final)           // L1: [NB][NH] fp32
{
    constexpr int KTOT = KIH + NH;
    constexpr int NCH_A = KIH / 32;
    constexpr int NCH_B = NH / 32;         // 16
    constexpr int ROWB = KTOT * 2;

    const int tid = threadIdx.x;
    const int hcol0 = wg * 8;

    // ---- stage weight slice into LDS (bf16, row-XOR swizzle) ----
    {
        constexpr int CPR = KTOT / 8;
        for (int cid = tid; cid < 32 * CPR; cid += 256) {
            const int r = cid / CPR;
            const int k0 = (cid - r * CPR) * 8;
            const int grow = (r >> 3) * NH + hcol0 + (r & 7);
            const float* src = (k0 < KIH) ? (W_ih + (size_t)grow * KIH + k0)
                                          : (W_hh + (size_t)grow * NH + (k0 - KIH));
            union { __bf16 h[8]; uint4 u; } tmp;
            #pragma unroll
            for (int j = 0; j < 8; ++j) tmp.h[j] = (__bf16)src[j];
            const unsigned off = (unsigned)(r * ROWB) +
                (((unsigned)(2 * k0)) ^ ((unsigned)((r & 7) << 4)));
            *(uint4*)(Wl + off) = tmp.u;
        }
    }

    // epilogue mapping: thread -> (batch eb, cols ecp..ecp+1); cell in registers
    const int eb = tid >> 2, ecp = (tid & 3) * 2;
    float bI[2], bF[2], bG[2], bO[2];
    #pragma unroll
    for (int j = 0; j < 2; ++j) {
        const int c = hcol0 + ecp + j;
        bI[j] = b_ih[c] + b_hh[c];
        bF[j] = b_ih[NH + c] + b_hh[NH + c];
        bG[j] = b_ih[2 * NH + c] + b_hh[2 * NH + c];
        bO[j] = b_ih[3 * NH + c] + b_hh[3 * NH + c];
    }
    float c0 = 0.f, c1 = 0.f;
    __syncthreads();

    // MFMA mapping: 4 waves = 4 batch-tiles; each wave does BOTH gate-tiles
    const int lane = tid & 63;
    const int wid = tid >> 6;
    const int bt = wid * 16;
    const int arow = bt + (lane & 15);
    const int q4 = ((lane >> 4) & 3) * 4;
    const char* wrow0 = Wl + (lane & 15) * ROWB;          // gate rows 0..15
    const char* wrow1 = wrow0 + 16 * ROWB;                // gate rows 16..31
    const unsigned bsz = (unsigned)((lane & 7) << 4);
    const int aoff = arow * 8 + (q4 & 4);
    const int bsub = (q4 >> 3);

    auto wfragp = [&](const char* wr, int k0) -> bf16x8 {
        const bf16x4 lo = *(const bf16x4*)(wr + (((unsigned)(2 * (k0 + q4))) ^ bsz));
        const bf16x4 hi = *(const bf16x4*)(wr + (((unsigned)(2 * (k0 + 16 + q4))) ^ bsz));
        return __builtin_shufflevector(lo, hi, 0, 1, 2, 3, 4, 5, 6, 7);
    };
    auto mk8 = [&](u64 a, u64 b) -> bf16x8 {
        bf16x4 lo, hi; __builtin_memcpy(&lo, &a, 8); __builtin_memcpy(&hi, &b, 8);
        return __builtin_shufflevector(lo, hi, 0, 1, 2, 3, 4, 5, 6, 7);
    };

    for (int t = 0; t < NT; ++t) {
        const __bf16* __restrict__ hprev;
        __bf16* __restrict__ hout;
        if constexpr (IS_L0 != 0) {
            hprev = (t == 0) ? hinit : (hrec0 + (size_t)(t - 1) * SREC);
            hout = hrec0 + (size_t)t * SREC;
        } else {
            hprev = (t == 0) ? hinit : (ring + (size_t)((t - 1) & (RING - 1)) * SREC);
            hout = ring + (size_t)(t & (RING - 1)) * SREC;
        }

        f32x4 p0a = {0,0,0,0}, p0b = {0,0,0,0};   // gate-tile 0, 2 chains
        f32x4 p1a = {0,0,0,0}, p1b = {0,0,0,0};   // gate-tile 1, 2 chains

        u64 rb[2 * NCH_B];
        issue_group<NCH_B>(hprev, aoff, bsub, rb);   // recurrence loads in flight

        if constexpr (IS_L0 != 0) {
            // phase A from x (cached, independent) overlaps recurrence arrival
            const float* xb = x_f32 + ((size_t)arow * NT + t) * KIH;
            #pragma unroll
            for (int kk = 0; kk < NCH_A; ++kk) {
                const float4 lo = *(const float4*)(xb + kk * 32 + q4);
                const float4 hi = *(const float4*)(xb + kk * 32 + 16 + q4);
                const bf16x4 alo = {(__bf16)lo.x, (__bf16)lo.y, (__bf16)lo.z, (__bf16)lo.w};
                const bf16x4 ahi = {(__bf16)hi.x, (__bf16)hi.y, (__bf16)hi.z, (__bf16)hi.w};
                const bf16x8 av = __builtin_shufflevector(alo, ahi, 0, 1, 2, 3, 4, 5, 6, 7);
                f32x4& d0 = (kk & 1) ? p0b : p0a;
                d0 = __builtin_amdgcn_mfma_f32_16x16x32_bf16(av, wfragp(wrow0, kk * 32), d0, 0, 0, 0);
                f32x4& d1 = (kk & 1) ? p1b : p1a;
                d1 = __builtin_amdgcn_mfma_f32_16x16x32_bf16(av, wfragp(wrow1, kk * 32), d1, 0, 0, 0);
            }
            if (t > 0) sweep_validate<NCH_B>(hprev, aoff, bsub, rb);
            #pragma unroll
            for (int kk = 0; kk < NCH_B; ++kk) {
                const bf16x8 av = mk8(rb[2 * kk], rb[2 * kk + 1]);
                f32x4& d0 = (kk & 1) ? p0b : p0a;
                d0 = __builtin_amdgcn_mfma_f32_16x16x32_bf16(av, wfragp(wrow0, KIH + kk * 32), d0, 0, 0, 0);
                f32x4& d1 = (kk & 1) ? p1b : p1a;
                d1 = __builtin_amdgcn_mfma_f32_16x16x32_bf16(av, wfragp(wrow1, KIH + kk * 32), d1, 0, 0, 0);
            }
        } else {
            // L1: input loads issued too; validate+MFMA recurrence FIRST
            // (own-layer data arrives early), input last (hides L0 straggler)
            u64 ra[2 * NCH_A];
            const __bf16* hA = hrec0 + (size_t)t * SREC;
            issue_group<NCH_A>(hA, aoff, bsub, ra);
            if (t > 0) sweep_validate<NCH_B>(hprev, aoff, bsub, rb);
            #pragma unroll
            for (int kk = 0; kk < NCH_B; ++kk) {
                const bf16x8 av = mk8(rb[2 * kk], rb[2 * kk + 1]);
                f32x4& d0 = (kk & 1) ? p0b : p0a;
                d0 = __builtin_amdgcn_mfma_f32_16x16x32_bf16(av, wfragp(wrow0, KIH + kk * 32), d0, 0, 0, 0);
                f32x4& d1 = (kk & 1) ? p1b : p1a;
                d1 = __builtin_amdgcn_mfma_f32_16x16x32_bf16(av, wfragp(wrow1, KIH + kk * 32), d1, 0, 0, 0);
            }
            sweep_validate<NCH_A>(hA, aoff, bsub, ra);
            #pragma unroll
            for (int kk = 0; kk < NCH_A; ++kk) {
                const bf16x8 av = mk8(ra[2 * kk], ra[2 * kk + 1]);
                f32x4& d0 = (kk & 1) ? p0b : p0a;
                d0 = __builtin_amdgcn_mfma_f32_16x16x32_bf16(av, wfragp(wrow0, kk * 32), d0, 0, 0, 0);
                f32x4& d1 = (kk & 1) ? p1b : p1a;
                d1 = __builtin_amdgcn_mfma_f32_16x16x32_bf16(av, wfragp(wrow1, kk * 32), d1, 0, 0, 0);
            }
        }

        const f32x4 s0 = p0a + p0b, s1 = p1a + p1b;
        __syncthreads();   // prev step's cell done reading gbuf (WAR)
        #pragma unroll
        for (int i = 0; i < 4; ++i) {
            gbuf[bt + ((lane >> 4) & 3) * 4 + i][lane & 15]        = s0[i];
            gbuf[bt + ((lane >> 4) & 3) * 4 + i][16 + (lane & 15)] = s1[i];
        }
        __syncthreads();   // gbuf ready

        // LSTM cell, fp32, 2 columns/thread; publish = fire-and-forget 4B store
        {
            float hh[2]; float cc[2] = {c0, c1};
            #pragma unroll
            for (int j = 0; j < 2; ++j) {
                const int c = ecp + j;
                const float gi = gbuf[eb][c]      + bI[j];
                const float gf = gbuf[eb][8 + c]  + bF[j];
                const float gg = gbuf[eb][16 + c] + bG[j];
                const float go = gbuf[eb][24 + c] + bO[j];
                const float ii = 1.f / (1.f + __expf(-gi));
                const float ff = 1.f / (1.f + __expf(-gf));
                const float g2 = 2.f / (1.f + __expf(-2.f * gg)) - 1.f;   // tanh
                const float oo = 1.f / (1.f + __expf(-go));
                const float cn = ff * cc[j] + ii * g2;
                const float th = 2.f / (1.f + __expf(-2.f * cn)) - 1.f;
                hh[j] = oo * th;
                cc[j] = cn;
            }
            c0 = cc[0]; c1 = cc[1];
            const u32 pk = (u32)bfbits(hh[0]) | ((u32)bfbits(hh[1]) << 16);
            sta4((u32*)(hout + (size_t)wg * BLK) + tid, pk);   // contiguous 1KB/WG
            if constexpr (IS_L0 == 0) {
                if (t >= 4)   // deferred re-canary of own 1KB in slot (t-4)&7
                    sta4((u32*)(ring + (size_t)((t - 4) & (RING - 1)) * SREC
                                + (size_t)wg * BLK) + tid, CAN32);
                if (t == NT - 1) {
                    h_final[(size_t)eb * NH + hcol0 + ecp]     = hh[0];
                    h_final[(size_t)eb * NH + hcol0 + ecp + 1] = hh[1];
                }
            }
        }
        // no drain, no flag, no barrier: next loop's sweeps order our stores
    }
}

__launch_bounds__(256, 2)
__global__ void lstm_fused_kernel(
    const float* W_ih0, const float* W_hh0, const float* b_ih0, const float* b_hh0,
    const float* W_ih1, const float* W_hh1, const float* b_ih1, const float* b_hh1,
    const float* x, __bf16* hrec0, __bf16* ring, __bf16* hinit, float* hfin)
{
    __shared__ __align__(16) char Wl[32 * 2048];    // 64KB (L0 uses 40KB)
    __shared__ float gbuf[64][36];

    if (blockIdx.x < NWG) {
        layer_body<128, 1>(Wl, gbuf, blockIdx.x,
                           W_ih0, W_hh0, b_ih0, b_hh0,
                           x, hrec0, nullptr, hinit, nullptr);
    } else {
        layer_body<512, 0>(Wl, gbuf, blockIdx.x - NWG,
                           W_ih1, W_hh1, b_ih1, b_hh1,
                           nullptr, hrec0, ring, hinit, hfin);
    }
}

__global__ void fc_kernel(const float* __restrict__ hfin,
                          const float* __restrict__ w_fc,
                          const float* __restrict__ b_fc,
                          float* __restrict__ out) {
    __shared__ float red[64][9];
    const int tid = threadIdx.x;
    const int b = tid >> 3, p = tid & 7;
    const int k0 = p * 64;
    float s = 0.f;
    #pragma unroll 8
    for (int k = 0; k < 64; ++k) s += hfin[(size_t)b * NH + k0 + k] * w_fc[k0 + k];
    red[b][p] = s;
    __syncthreads();
    if (p == 0) {
        float a = 0.f;
        #pragma unroll
        for (int j = 0; j < 8; ++j) a += red[b][j];
        out[b] = a + b_fc[0];
    }
}

extern "C" void kernel_launch(void* const* d_in, const int* in_sizes, int n_in,
                              void* d_out, int out_size, void* d_ws, size_t ws_size,
                              hipStream_t stream) {
    const float* x     = (const float*)d_in[0];
    const float* W_ih0 = (const float*)d_in[1];
    const float* W_hh0 = (const float*)d_in[2];
    const float* b_ih0 = (const float*)d_in[3];
    const float* b_hh0 = (const float*)d_in[4];
    const float* W_ih1 = (const float*)d_in[5];
    const float* W_hh1 = (const float*)d_in[6];
    const float* b_ih1 = (const float*)d_in[7];
    const float* b_hh1 = (const float*)d_in[8];
    const float* W_fc  = (const float*)d_in[9];
    const float* b_fc  = (const float*)d_in[10];

    // workspace layout (bytes); total ~34.3 MB (proven budget)
    char* ws = (char*)d_ws;
    __bf16* hrec0 = (__bf16*)(ws);                        // 512*32768*2 = 33,554,432
    __bf16* ring  = (__bf16*)(ws + 33554432);             // 8*32768*2   = 524,288
    __bf16* hinit = (__bf16*)(ws + 33554432 + 524288);    // 32768*2     = 65,536
    float*  hfin  = (float*) (ws + 33554432 + 589824);    // 64*512*4    = 131,072

    prep_kernel<<<dim3(2048), dim3(256), 0, stream>>>(
        (u64*)hrec0, (u64*)ring, (u64*)hinit);

    lstm_fused_kernel<<<dim3(2 * NWG), dim3(256), 0, stream>>>(
        W_ih0, W_hh0, b_ih0, b_hh0, W_ih1, W_hh1, b_ih1, b_hh1,
        x, hrec0, ring, hinit, hfin);

    fc_kernel<<<dim3(1), dim3(512), 0, stream>>>(hfin, W_fc, b_fc, (float*)d_out);
}

// Round 11
// 3978.680 us; speedup vs baseline: 2.1772x; 2.1772x over previous
//
#include <hip/hip_runtime.h>

// LSTMClassification: B=64, T=512, IN=128, H=512, 2 layers + FC(512->1)
// Round 11 = round-9 champion body + XCD-local intra-layer exchange.
//   Mechanism: vector L1 is write-through -> plain stores commit to the XCD's
//   L2; plain loads of FIRST-TOUCH (step-indexed) addresses cannot be stale.
//   If a layer's 64 WGs are co-XCD (residue-class placement), intra-layer h
//   moves at L2 latency (~0.3us) instead of MALL-bypass RT (~1.5us).
//   Flags stay AGENT-scope (proven). Chain: 3.5 MALL RT -> ~1 RT + 2 L2 hops.
// Safety rails (round-6 lesson: never bet on unverified semantics):
//   1) runtime PROBE: each WG plain-stores nonce^hash(wg); partner (same
//      residue class) plain-loads it after a proven AGENT handshake; votes via
//      AGENT ops; ANY failure -> AGENT fallback (== champion). Nonce from
//      clock64() so replay-stale values can't false-accept.
//   2) ws_size gated host-side: L1's step-indexed buffer needs 33.5MB extra;
//      if ws < 68MB -> parity-buffer AGENT layout (exact champion).
//   3) inter-layer (L0->L1) stays AGENT. flagB (h0 MALL-visible) is derived
//      FREE from vmcnt in-order completion: at step t's vmcnt(1), all agent
//      stores of step t-1 are provably complete -> flagB=t costs nothing.
//      L1 prefetches h0[t+1] into registers each step (flagB >= t+2 gated),
//      so the cross-XCD data hop is fully off L1's critical chain.

#define NWG 64
#define NB 64
#define NT 512
#define NH 512
#define BLK 512                 // elements per WG h-block (64 batches x 8 cols)
#define SREC (NWG * BLK)        // elements per step slot = 32768
#define FPAD 16                 // 64B padding stride for flags/ctrl words

typedef float f32x4 __attribute__((ext_vector_type(4)));
typedef __bf16 bf16x4 __attribute__((ext_vector_type(4)));
typedef __bf16 bf16x8 __attribute__((ext_vector_type(8)));
typedef unsigned long long u64;
typedef unsigned u32;

// ---- proven AGENT-scope (MALL) primitives ----
__device__ __forceinline__ u64 ld8a(const __bf16* p) {
    return __hip_atomic_load((const u64*)p, __ATOMIC_RELAXED, __HIP_MEMORY_SCOPE_AGENT);
}
__device__ __forceinline__ void st8a(__bf16* p, u64 v) {
    __hip_atomic_store((u64*)p, v, __ATOMIC_RELAXED, __HIP_MEMORY_SCOPE_AGENT);
}
__device__ __forceinline__ u32 ldfa(const u32* p) {
    return __hip_atomic_load(p, __ATOMIC_RELAXED, __HIP_MEMORY_SCOPE_AGENT);
}
__device__ __forceinline__ void stfa(u32* p, u32 v) {
    __hip_atomic_store(p, v, __ATOMIC_RELAXED, __HIP_MEMORY_SCOPE_AGENT);
}
// ---- plain (L2 write-through / first-touch cached) primitives ----
__device__ __forceinline__ u64 ld8p(const __bf16* p) { return *(const u64*)p; }
__device__ __forceinline__ void st8p(__bf16* p, u64 v) { *(u64*)p = v; }

__device__ __forceinline__ unsigned short bfbits(float f) {
    __bf16 h = (__bf16)f; unsigned short u; __builtin_memcpy(&u, &h, 2); return u;
}

// wave0 polls 64 padded flags until all >= ta
__device__ __forceinline__ void wait_one(const u32* f, u32 ta, int lane) {
    int g = 0;
    for (;;) {
        u32 a = ldfa(&f[lane * FPAD]);
        if (__all((int)(a >= ta))) break;
        if (++g > (1 << 17)) break;
    }
}
// wave0 polls two padded flag arrays until all fA>=ta AND all fB>=tb
__device__ __forceinline__ void wait_two(const u32* fA, u32 ta, const u32* fB, u32 tb, int lane) {
    int g = 0;
    for (;;) {
        u32 a = ldfa(&fA[lane * FPAD]);
        u32 b = ldfa(&fB[lane * FPAD]);
        if (__all((int)(a >= ta && b >= tb))) break;
        if (++g > (1 << 17)) break;
    }
}

// ctrl layout (u32 indices, all padded x16)
#define CT_FLA0   0            // 64*16
#define CT_FLA1   1024
#define CT_FLB    2048
#define CT_NONCE  3072         // 2*16
#define CT_PRF    3104         // 128*16 probe-ready flags
#define CT_VOTE   5152         // 128*16 votes
#define CT_PBUF   7200         // 128*16 probe values (plain path)
#define CT_N      9248

__global__ void prep_kernel(unsigned short* hinit, unsigned short* hpar, u32* ctrl) {
    int i = blockIdx.x * blockDim.x + threadIdx.x;
    if (i < SREC) hinit[i] = 0;                        // zero h_{-1}
    if (hpar != nullptr && i < 2 * SREC) hpar[i] = 0;  // parity buffer (small-ws L1)
    for (int k = i; k < CT_N; k += gridDim.x * blockDim.x) ctrl[k] = 0;
}

// ---- visibility probe: tests plain-store -> plain-load across WG pairs ----
__device__ bool run_probe(int layer, int wg, int tid, u32* ctrl, int allowFast) {
    __shared__ int verd;
    if (!allowFast) { if (tid == 0) verd = 0; __syncthreads(); return false; }
    const int gwg = layer * NWG + wg;
    if (tid == 0) {
        if (wg == 0) {
            u32 n = ((u32)clock64()) | 1u;
            stfa(&ctrl[CT_NONCE + layer * FPAD], n);
        }
        u32 nonce = 0; int g = 0;
        while ((nonce = ldfa(&ctrl[CT_NONCE + layer * FPAD])) == 0u)
            { if (++g > (1 << 12)) break; }
        u32 ok = 0;
        if (nonce != 0u) {
            // plain store of nonce-derived value (the path under test)
            ctrl[CT_PBUF + gwg * FPAD] = nonce ^ ((u32)wg * 2654435761u);
            asm volatile("s_waitcnt vmcnt(0)" ::: "memory");
            stfa(&ctrl[CT_PRF + gwg * FPAD], nonce);          // proven ready flag
            const int p = (wg + 1) & (NWG - 1);
            const int gp = layer * NWG + p;
            u32 f = 0; g = 0;
            while ((f = ldfa(&ctrl[CT_PRF + gp * FPAD])) != nonce)
                { if (++g > (1 << 13)) break; }
            if (f == nonce) {
                asm volatile("" ::: "memory");
                u32 got = ctrl[CT_PBUF + gp * FPAD];          // plain first-touch load
                asm volatile("" ::: "memory");
                ok = (got == (nonce ^ ((u32)p * 2654435761u))) ? 1u : 0u;
            }
        }
        stfa(&ctrl[CT_VOTE + gwg * FPAD], ok ? 1u : 2u);
    }
    int fastv = 0;
    if (tid < 64) {
        u32 v = 2u; int g = 0;
        for (;;) {
            v = ldfa(&ctrl[CT_VOTE + (layer * NWG + tid) * FPAD]);
            if (__all((int)(v != 0u))) break;
            if (++g > (1 << 14)) { v = 2u; break; }
        }
        fastv = __all((int)(v == 1u)) ? 1 : 0;
        if (tid == 0) verd = fastv;
    }
    __syncthreads();
    return verd != 0;
}

template<int KIH, int IS_L0, bool FAST, bool STEPIDX>
__device__ void layer_loop(
    char* Wl, float (*gbuf)[36], u32 (*hstage32)[4], int wg,
    const float* __restrict__ W_ih, const float* __restrict__ W_hh,
    const float* __restrict__ b_ih, const float* __restrict__ b_hh,
    const float* __restrict__ x_f32,       // L0 only
    const __bf16* __restrict__ hrec_dep,   // L1: hrec0 [NT][NWG][BLK] (AGENT/MALL)
    __bf16* __restrict__ hself,            // own-layer h (step-indexed or parity)
    const __bf16* __restrict__ hinit,      // zero block
    float* __restrict__ h_final,           // L1 only
    u32* __restrict__ flA_self,            // [64*FPAD] intra-layer flags
    u32* __restrict__ flB)                 // [64*FPAD] L0 writes / L1 reads
{
    constexpr int KTOT = KIH + NH;
    constexpr int NCH_A = KIH / 32;
    constexpr int NCH_B = NH / 32;         // 16
    constexpr int ROWB = KTOT * 2;

    const int tid = threadIdx.x;
    const int hcol0 = wg * 8;

    // ---- stage weight slice into LDS (bf16, row-XOR swizzle) ----
    {
        constexpr int CPR = KTOT / 8;
        for (int cid = tid; cid < 32 * CPR; cid += 256) {
            const int r = cid / CPR;
            const int k0 = (cid - r * CPR) * 8;
            const int grow = (r >> 3) * NH + hcol0 + (r & 7);
            const float* src = (k0 < KIH) ? (W_ih + (size_t)grow * KIH + k0)
                                          : (W_hh + (size_t)grow * NH + (k0 - KIH));
            union { __bf16 h[8]; uint4 u; } tmp;
            #pragma unroll
            for (int j = 0; j < 8; ++j) tmp.h[j] = (__bf16)src[j];
            const unsigned off = (unsigned)(r * ROWB) +
                (((unsigned)(2 * k0)) ^ ((unsigned)((r & 7) << 4)));
            *(uint4*)(Wl + off) = tmp.u;
        }
    }

    // epilogue mapping; biases folded; cell state in registers
    const int eb = tid >> 2, ecp = (tid & 3) * 2;
    float bI[2], bF[2], bG[2], bO[2];
    #pragma unroll
    for (int j = 0; j < 2; ++j) {
        const int c = hcol0 + ecp + j;
        bI[j] = b_ih[c] + b_hh[c];
        bF[j] = b_ih[NH + c] + b_hh[NH + c];
        bG[j] = b_ih[2 * NH + c] + b_hh[2 * NH + c];
        bO[j] = b_ih[3 * NH + c] + b_hh[3 * NH + c];
    }
    float c0 = 0.f, c1 = 0.f;
    __syncthreads();

    // MFMA mapping: 4 waves = 4 batch-tiles; each wave does BOTH gate-tiles
    const int lane = tid & 63;
    const int wid = tid >> 6;
    const int bt = wid * 16;
    const int arow = bt + (lane & 15);
    const int q4 = ((lane >> 4) & 3) * 4;
    const char* wrow0 = Wl + (lane & 15) * ROWB;
    const char* wrow1 = wrow0 + 16 * ROWB;
    const unsigned bsz = (unsigned)((lane & 7) << 4);
    const int aoff = arow * 8 + (q4 & 4);
    const int bsub = (q4 >> 3);

    auto wfragp = [&](const char* wr, int k0) -> bf16x8 {
        const bf16x4 lo = *(const bf16x4*)(wr + (((unsigned)(2 * (k0 + q4))) ^ bsz));
        const bf16x4 hi = *(const bf16x4*)(wr + (((unsigned)(2 * (k0 + 16 + q4))) ^ bsz));
        return __builtin_shufflevector(lo, hi, 0, 1, 2, 3, 4, 5, 6, 7);
    };
    auto mk8 = [&](u64 a, u64 b) -> bf16x8 {
        bf16x4 lo, hi; __builtin_memcpy(&lo, &a, 8); __builtin_memcpy(&hi, &b, 8);
        return __builtin_shufflevector(lo, hi, 0, 1, 2, 3, 4, 5, 6, 7);
    };

    // L1: register prefetch of h0[t] (AGENT loads, issued one step early)
    u64 ra[2 * NCH_A];
    if constexpr (IS_L0 == 0) {
        if (wid == 0) wait_one(flB, 1u, lane);     // h0[0] MALL-visible
        __syncthreads();
        #pragma unroll
        for (int kk = 0; kk < NCH_A; ++kk) {
            const __bf16* base = hrec_dep + (4 * kk + bsub) * BLK + aoff;
            ra[2 * kk]     = ld8a(base);
            ra[2 * kk + 1] = ld8a(base + 2 * BLK);
        }
    }

    for (int t = 0; t < NT; ++t) {
        const __bf16* hprev;
        __bf16* hout;
        if constexpr (STEPIDX) {
            hprev = (t == 0) ? hinit : (hself + (size_t)(t - 1) * SREC);
            hout = hself + (size_t)t * SREC;
        } else {
            hprev = hself + (size_t)(t & 1) * SREC;
            hout = hself + (size_t)((t + 1) & 1) * SREC;
        }

        f32x4 p0a = {0,0,0,0}, p0b = {0,0,0,0};
        f32x4 p1a = {0,0,0,0}, p1b = {0,0,0,0};

        if constexpr (IS_L0 != 0) {
            // phase A from x (cached, independent) BEFORE the wait
            const float* xb = x_f32 + ((size_t)arow * NT + t) * KIH;
            #pragma unroll
            for (int kk = 0; kk < NCH_A; ++kk) {
                const float4 lo = *(const float4*)(xb + kk * 32 + q4);
                const float4 hi = *(const float4*)(xb + kk * 32 + 16 + q4);
                const bf16x4 alo = {(__bf16)lo.x, (__bf16)lo.y, (__bf16)lo.z, (__bf16)lo.w};
                const bf16x4 ahi = {(__bf16)hi.x, (__bf16)hi.y, (__bf16)hi.z, (__bf16)hi.w};
                const bf16x8 av = __builtin_shufflevector(alo, ahi, 0, 1, 2, 3, 4, 5, 6, 7);
                f32x4& d0 = (kk & 1) ? p0b : p0a;
                d0 = __builtin_amdgcn_mfma_f32_16x16x32_bf16(av, wfragp(wrow0, kk * 32), d0, 0, 0, 0);
                f32x4& d1 = (kk & 1) ? p1b : p1a;
                d1 = __builtin_amdgcn_mfma_f32_16x16x32_bf16(av, wfragp(wrow1, kk * 32), d1, 0, 0, 0);
            }
            if (t > 0 && wid == 0) wait_one(flA_self, (u32)t, lane);
            __syncthreads();
        } else {
            if (wid == 0) {
                const u32 tb = (t <= NT - 2) ? (u32)(t + 2) : 0u;   // gate next prefetch
                wait_two(flA_self, (t > 0) ? (u32)t : 0u, flB, tb, lane);
            }
            __syncthreads();
        }

        // recurrence loads (fast: plain/L2-local; fallback: agent)
        u64 rb[2 * NCH_B];
        #pragma unroll
        for (int kk = 0; kk < NCH_B; ++kk) {
            const __bf16* base = hprev + (4 * kk + bsub) * BLK + aoff;
            if constexpr (FAST) { rb[2*kk] = ld8p(base); rb[2*kk+1] = ld8p(base + 2*BLK); }
            else                { rb[2*kk] = ld8a(base); rb[2*kk+1] = ld8a(base + 2*BLK); }
        }
        // L1: input MFMAs from prefetched REGISTERS (no memory wait) while rb flies
        if constexpr (IS_L0 == 0) {
            #pragma unroll
            for (int kk = 0; kk < NCH_A; ++kk) {
                const bf16x8 av = mk8(ra[2 * kk], ra[2 * kk + 1]);
                f32x4& d0 = (kk & 1) ? p0b : p0a;
                d0 = __builtin_amdgcn_mfma_f32_16x16x32_bf16(av, wfragp(wrow0, kk * 32), d0, 0, 0, 0);
                f32x4& d1 = (kk & 1) ? p1b : p1a;
                d1 = __builtin_amdgcn_mfma_f32_16x16x32_bf16(av, wfragp(wrow1, kk * 32), d1, 0, 0, 0);
            }
        }
        #pragma unroll
        for (int kk = 0; kk < NCH_B; ++kk) {
            const bf16x8 av = mk8(rb[2 * kk], rb[2 * kk + 1]);
            f32x4& d0 = (kk & 1) ? p0b : p0a;
            d0 = __builtin_amdgcn_mfma_f32_16x16x32_bf16(av, wfragp(wrow0, KIH + kk * 32), d0, 0, 0, 0);
            f32x4& d1 = (kk & 1) ? p1b : p1a;
            d1 = __builtin_amdgcn_mfma_f32_16x16x32_bf16(av, wfragp(wrow1, KIH + kk * 32), d1, 0, 0, 0);
        }

        const f32x4 s0 = p0a + p0b, s1 = p1a + p1b;
        #pragma unroll
        for (int i = 0; i < 4; ++i) {
            gbuf[bt + ((lane >> 4) & 3) * 4 + i][lane & 15]        = s0[i];
            gbuf[bt + ((lane >> 4) & 3) * 4 + i][16 + (lane & 15)] = s1[i];
        }
        __syncthreads();

        // LSTM cell, fp32, 2 columns per thread (gate order i, f, g, o)
        {
            float hh[2]; float cc[2] = {c0, c1};
            #pragma unroll
            for (int j = 0; j < 2; ++j) {
                const int c = ecp + j;
                const float gi = gbuf[eb][c]      + bI[j];
                const float gf = gbuf[eb][8 + c]  + bF[j];
                const float gg = gbuf[eb][16 + c] + bG[j];
                const float go = gbuf[eb][24 + c] + bO[j];
                const float ii = 1.f / (1.f + __expf(-gi));
                const float ff = 1.f / (1.f + __expf(-gf));
                const float g2 = 2.f / (1.f + __expf(-2.f * gg)) - 1.f;
                const float oo = 1.f / (1.f + __expf(-go));
                const float cn = ff * cc[j] + ii * g2;
                const float th = 2.f / (1.f + __expf(-2.f * cn)) - 1.f;
                hh[j] = oo * th;
                cc[j] = cn;
            }
            c0 = cc[0]; c1 = cc[1];
            hstage32[eb][tid & 3] = (u32)bfbits(hh[0]) | ((u32)bfbits(hh[1]) << 16);
            if constexpr (IS_L0 == 0) {
                if (t == NT - 1) {
                    h_final[(size_t)eb * NH + hcol0 + ecp]     = hh[0];
                    h_final[(size_t)eb * NH + hcol0 + ecp + 1] = hh[1];
                }
            }
        }
        __syncthreads();   // hstage ready

        // publish this WG's contiguous 1KB block
        if (tid < 128) {
            const u64 v = ((const u64*)hstage32)[tid];
            __bf16* dst = hout + (size_t)wg * BLK + (size_t)tid * 4;
            if constexpr (FAST) {
                st8p(dst, v);                       // XCD L2 (intra-layer consumers)
                if constexpr (IS_L0 != 0) st8a(dst, v);   // MALL copy (for L1)
            } else {
                st8a(dst, v);
            }
        }
        // drain: FAST-L0 waits only the PLAIN store (oldest); the agent store
        // completes in background -- vmcnt counts oldest-first, so at the NEXT
        // step's vmcnt(1), agent(t-1) is provably complete -> flagB is free.
        if constexpr (FAST && IS_L0 != 0) asm volatile("s_waitcnt vmcnt(1)" ::: "memory");
        else                              asm volatile("s_waitcnt vmcnt(0)" ::: "memory");
        __syncthreads();
        if (tid == 0) {
            stfa(&flA_self[wg * FPAD], (u32)(t + 1));
            if constexpr (IS_L0 != 0)
                stfa(&flB[wg * FPAD], FAST ? (u32)t : (u32)(t + 1));
        }
        // L1: prefetch next input h0[t+1] (AGENT; lands during next poll)
        if constexpr (IS_L0 == 0) {
            if (t < NT - 1) {
                const __bf16* hA = hrec_dep + (size_t)(t + 1) * SREC;
                #pragma unroll
                for (int kk = 0; kk < NCH_A; ++kk) {
                    const __bf16* base = hA + (4 * kk + bsub) * BLK + aoff;
                    ra[2 * kk]     = ld8a(base);
                    ra[2 * kk + 1] = ld8a(base + 2 * BLK);
                }
            }
        }
    }

    if constexpr (IS_L0 != 0) {   // final flagB: attest h0[511] at MALL
        asm volatile("s_waitcnt vmcnt(0)" ::: "memory");
        __syncthreads();
        if (tid == 0) stfa(&flB[wg * FPAD], (u32)NT);
    }
}

__launch_bounds__(256, 2)
__global__ void lstm_kernel(
    const float* W_ih0, const float* W_hh0, const float* b_ih0, const float* b_hh0,
    const float* W_ih1, const float* W_hh1, const float* b_ih1, const float* b_hh1,
    const float* x, __bf16* hrec0, __bf16* h1buf, const __bf16* hinit, float* hfin,
    u32* ctrl, int allowFastL0, int allowFastL1, int stepIdxL1)
{
    __shared__ __align__(16) char Wl[32 * 2048];
    __shared__ float gbuf[64][36];
    __shared__ u32 hstage32[64][4];

    const int res = blockIdx.x & 7;
    if (res > 1) return;                       // dead block (no barriers crossed)
    const int wg = (int)(blockIdx.x >> 3);
    const int tid = threadIdx.x;

    u32* flA0 = ctrl + CT_FLA0;
    u32* flA1 = ctrl + CT_FLA1;
    u32* flB  = ctrl + CT_FLB;

    if (res == 0) {
        const bool f = run_probe(0, wg, tid, ctrl, allowFastL0);
        if (f) layer_loop<128, 1, true,  true>(Wl, gbuf, hstage32, wg,
                   W_ih0, W_hh0, b_ih0, b_hh0, x, nullptr, hrec0, hinit, nullptr, flA0, flB);
        else   layer_loop<128, 1, false, true>(Wl, gbuf, hstage32, wg,
                   W_ih0, W_hh0, b_ih0, b_hh0, x, nullptr, hrec0, hinit, nullptr, flA0, flB);
    } else {
        const bool f = run_probe(1, wg, tid, ctrl, allowFastL1);
        if (stepIdxL1 != 0) {
            if (f) layer_loop<512, 0, true,  true>(Wl, gbuf, hstage32, wg,
                       W_ih1, W_hh1, b_ih1, b_hh1, nullptr, hrec0, h1buf, hinit, hfin, flA1, flB);
            else   layer_loop<512, 0, false, true>(Wl, gbuf, hstage32, wg,
                       W_ih1, W_hh1, b_ih1, b_hh1, nullptr, hrec0, h1buf, hinit, hfin, flA1, flB);
        } else {
            layer_loop<512, 0, false, false>(Wl, gbuf, hstage32, wg,
                       W_ih1, W_hh1, b_ih1, b_hh1, nullptr, hrec0, h1buf, hinit, hfin, flA1, flB);
        }
    }
}

__global__ void fc_kernel(const float* __restrict__ hfin,
                          const float* __restrict__ w_fc,
                          const float* __restrict__ b_fc,
                          float* __restrict__ out) {
    __shared__ float red[64][9];
    const int tid = threadIdx.x;
    const int b = tid >> 3, p = tid & 7;
    const int k0 = p * 64;
    float s = 0.f;
    #pragma unroll 8
    for (int k = 0; k < 64; ++k) s += hfin[(size_t)b * NH + k0 + k] * w_fc[k0 + k];
    red[b][p] = s;
    __syncthreads();
    if (p == 0) {
        float a = 0.f;
        #pragma unroll
        for (int j = 0; j < 8; ++j) a += red[b][j];
        out[b] = a + b_fc[0];
    }
}

extern "C" void kernel_launch(void* const* d_in, const int* in_sizes, int n_in,
                              void* d_out, int out_size, void* d_ws, size_t ws_size,
                              hipStream_t stream) {
    const float* x     = (const float*)d_in[0];
    const float* W_ih0 = (const float*)d_in[1];
    const float* W_hh0 = (const float*)d_in[2];
    const float* b_ih0 = (const float*)d_in[3];
    const float* b_hh0 = (const float*)d_in[4];
    const float* W_ih1 = (const float*)d_in[5];
    const float* W_hh1 = (const float*)d_in[6];
    const float* b_ih1 = (const float*)d_in[7];
    const float* b_hh1 = (const float*)d_in[8];
    const float* W_fc  = (const float*)d_in[9];
    const float* b_fc  = (const float*)d_in[10];

    char* ws = (char*)d_ws;
    size_t off = 0;
    auto take = [&](size_t bytes) { char* p = ws + off; off += (bytes + 255) & ~(size_t)255; return p; };

    __bf16* hrec0 = (__bf16*)take((size_t)NT * SREC * 2);   // 33,554,432
    __bf16* hinit = (__bf16*)take(SREC * 2);                // 65,536
    float*  hfin  = (float*) take(NB * NH * 4);             // 131,072
    u32*    ctrl  = (u32*)   take(CT_N * 4);                // ~37KB
    const size_t base = off;
    const size_t need_big = base + (size_t)NT * SREC * 2;   // + 33.5MB for hrec1

    const bool big = (ws_size >= need_big);
    __bf16* h1buf;
    unsigned short* hpar_for_prep = nullptr;
    if (big) {
        h1buf = (__bf16*)take((size_t)NT * SREC * 2);       // step-indexed hrec1
    } else {
        h1buf = (__bf16*)take((size_t)2 * SREC * 2);        // parity buffer (champion)
        hpar_for_prep = (unsigned short*)h1buf;
    }

    prep_kernel<<<dim3(256), dim3(256), 0, stream>>>(
        (unsigned short*)hinit, hpar_for_prep, ctrl);

    lstm_kernel<<<dim3(512), dim3(256), 0, stream>>>(
        W_ih0, W_hh0, b_ih0, b_hh0, W_ih1, W_hh1, b_ih1, b_hh1,
        x, hrec0, h1buf, hinit, hfin, ctrl,
        /*allowFastL0=*/1, /*allowFastL1=*/big ? 1 : 0, /*stepIdxL1=*/big ? 1 : 0);

    fc_kernel<<<dim3(1), dim3(512), 0, stream>>>(hfin, W_fc, b_fc, (float*)d_out);
}